// Round 5
// baseline (575.134 us; speedup 1.0000x reference)
//
#include <hip/hip_runtime.h>
#include <math.h>

#define HIDDEN   1024
#define IN_DIM   1152
#define OUT_D    512
#define EPS_C    1e-4f
#define BMA      64
#define OUT_BLK_BYTES 131072   // 64 rows * 512 f32
#define PREP_BYTES    81920    // 80 frags * 1024 B per block (x0: 16, extra: 64)

typedef __attribute__((ext_vector_type(8))) __bf16 bf16x8;
typedef __attribute__((ext_vector_type(4))) float  f32x4;

#define MFMA16(a, b, c) __builtin_amdgcn_mfma_f32_16x16x32_bf16(a, b, c, 0, 0, 0)

static __device__ __forceinline__ unsigned short f2bf(float f) {
    union { float f; unsigned u; } v; v.f = f;
    unsigned r = v.u + 0x7fffu + ((v.u >> 16) & 1u);
    return (unsigned short)(r >> 16);
}

static __device__ __forceinline__ uint4 pack8(const float* v) {
    uint4 p;
    p.x = (unsigned)f2bf(v[0]) | ((unsigned)f2bf(v[1]) << 16);
    p.y = (unsigned)f2bf(v[2]) | ((unsigned)f2bf(v[3]) << 16);
    p.z = (unsigned)f2bf(v[4]) | ((unsigned)f2bf(v[5]) << 16);
    p.w = (unsigned)f2bf(v[6]) | ((unsigned)f2bf(v[7]) << 16);
    return p;
}

// tanh-form GELU via sigmoid: g = v * sigmoid(c1*v + c3*v^3), max err ~1e-3
static __device__ __forceinline__ float gelu_f(float v) {
    const float t = -v * (1.5957691216f + 0.0713548163f * v * v);
    return v / (1.0f + __expf(t));
}

// ============ prep: pack W1 (k-major-permuted rows), W2, and per-block x0+extra ============
// Fragment (kt, nt): lane holds B[kt*32 + 8*(lane>>4) + i][nt*16 + (lane&15)], i=0..7,
// stored frag*512 + lane*8 ushorts. A-frags for x0/extra use the same lane mapping
// (row = mt*16 + (lane&15), k = 8*(lane>>4) + i within a 32-col chunk).
__global__ void prep_kernel(const float* __restrict__ W1, const float* __restrict__ W2,
                            const float* __restrict__ x, const float* __restrict__ extra,
                            unsigned short* __restrict__ w1p, unsigned short* __restrict__ w2p,
                            char* __restrict__ pmain, char* __restrict__ pspill,
                            int nrows, int nblk, int spill_start) {
    const int tid  = blockIdx.x * 256 + threadIdx.x;
    const int frag = tid >> 6;
    const int lane = tid & 63;
    if (frag < 3328) {
        // ---- weight packing ----
        const float* W; unsigned short* outp; int Ndim, nt, kt, fl; bool perm;
        if (frag < 2304) { W = W1; outp = w1p; Ndim = 1024; fl = frag;        nt = fl & 63; kt = fl >> 6; perm = true;  }
        else             { W = W2; outp = w2p; Ndim = 512;  fl = frag - 2304; nt = fl & 31; kt = fl >> 5; perm = false; }
        const int k0 = kt * 32 + ((lane >> 4) << 3);
        const int n  = nt * 16 + (lane & 15);
        float v[8];
#pragma unroll
        for (int i = 0; i < 8; ++i) {
            int kp = k0 + i, ko = kp;
            if (perm && kp >= 128 && kp < 512) { const int q = kp - 128; ko = 128 + (q & 127) * 3 + (q >> 7); }
            v[i] = W[(size_t)ko * Ndim + n];
        }
        *reinterpret_cast<uint4*>(outp + (size_t)fl * 512 + lane * 8) = pack8(v);
    } else {
        // ---- per-block x0/extra prepack ----
        const int fp = frag - 3328;
        const int b  = fp / 80;
        if (b >= nblk) return;
        const int fl = fp - b * 80;
        const int mt = fl & 3;
        const int row = b * 64 + mt * 16 + (lane & 15);
        const float* src = (fl < 16) ? (x     + (size_t)row * 512 + (fl >> 2) * 32)
                                     : (extra + (size_t)row * 512 + ((fl - 16) >> 2) * 32);
        float v[8];
#pragma unroll
        for (int i = 0; i < 8; ++i) v[i] = 0.0f;
        if (row < nrows) {
            const float* p = src + (lane >> 4) * 8;
            float4 lo = *reinterpret_cast<const float4*>(p);
            float4 hi = *reinterpret_cast<const float4*>(p + 4);
            v[0]=lo.x; v[1]=lo.y; v[2]=lo.z; v[3]=lo.w;
            v[4]=hi.x; v[5]=hi.y; v[6]=hi.z; v[7]=hi.w;
        }
        char* base = (b < spill_start) ? (pmain + (size_t)b * OUT_BLK_BYTES)
                                       : (pspill + (size_t)(b - spill_start) * PREP_BYTES);
        *reinterpret_cast<uint4*>(base + fl * 1024 + lane * 16) = pack8(v);
    }
}

// ===================== fused: DMA-stage + features + GEMM1 + GELU + GEMM2 + rotation =====================
__global__ __launch_bounds__(1024, 4)
void fused_kernel(const float* __restrict__ x, const float* __restrict__ rot,
                  const float* __restrict__ b1, const float* __restrict__ b2,
                  const bf16x8* __restrict__ w1p, const bf16x8* __restrict__ w2p,
                  const char* __restrict__ pmain, const char* __restrict__ pspill,
                  float* __restrict__ out, int nrows, int spill_start) {
    // x1 A-frag image: 36 kt x 4 mt x 1KB = 147456 B; h frags (131072 B) alias kt 0..31
    __shared__ __align__(16) unsigned short buf[36 * 4 * 512];
    __shared__ float R_s[BMA * 9];

    const int tid  = threadIdx.x;
    const int bid  = blockIdx.x;
    const int row0 = bid * BMA;
    const int w    = tid >> 6;   // wave 0..15
    const int lane = tid & 63;
    const int lr   = lane & 15;
    const int lk   = lane >> 4;

    // ---------------- phase 0: issue all x0/extra DMAs (global -> LDS direct) ----------------
    {
        const char* pbase = (bid < spill_start) ? (pmain + (size_t)bid * OUT_BLK_BYTES)
                                                : (pspill + (size_t)(bid - spill_start) * PREP_BYTES);
#pragma unroll
        for (int q = 0; q < 5; ++q) {
            const int fl  = w * 5 + q;                               // 0..79
            const int ktg = (fl < 16) ? (fl >> 2) : (16 + (fl >> 2)); // x0 -> kt 0..3, extra -> kt 20..35
            const int mt  = fl & 3;
            __builtin_amdgcn_global_load_lds(
                (const __attribute__((address_space(1))) unsigned int*)(pbase + fl * 1024 + lane * 16),
                (__attribute__((address_space(3))) unsigned int*)(buf + (ktg * 4 + mt) * 512),
                16, 0, 0);
        }
    }

    // ---------------- phase 1: vec_local (k-major) + vec_norm -> kt 4..19 ----------------
    {
        const int m   = tid >> 4;
        const int l16 = tid & 15;
        const int mt  = m >> 4;
        const int r8u = (m & 15) * 8;
        int i = row0 + m; if (i > nrows - 1) i = nrows - 1;
        float r[9];
#pragma unroll
        for (int q = 0; q < 9; ++q) r[q] = rot[(size_t)i * 9 + q];
        if (l16 < 9) R_s[m * 9 + l16] = r[l16];
        const float* xp = x + (size_t)i * 512 + l16 * 8;
        float xv[3][8];
#pragma unroll
        for (int c = 0; c < 3; ++c) {
            float4 lo = *reinterpret_cast<const float4*>(xp + (c + 1) * 128);
            float4 hi = *reinterpret_cast<const float4*>(xp + (c + 1) * 128 + 4);
            xv[c][0]=lo.x; xv[c][1]=lo.y; xv[c][2]=lo.z; xv[c][3]=lo.w;
            xv[c][4]=hi.x; xv[c][5]=hi.y; xv[c][6]=hi.z; xv[c][7]=hi.w;
        }
        auto stw = [&](int k0v, const float* v8) {
            *reinterpret_cast<uint4*>(buf + ((k0v >> 5) * 4 + mt) * 512 + ((k0v >> 3) & 3) * 128 + r8u) = pack8(v8);
        };
#pragma unroll
        for (int kk = 0; kk < 3; ++kk) {
            float vl[8];
#pragma unroll
            for (int j = 0; j < 8; ++j)
                vl[j] = xv[0][j] * r[kk] + xv[1][j] * r[3 + kk] + xv[2][j] * r[6 + kk];
            stw(128 + kk * 128 + l16 * 8, vl);
        }
        float nv[8];
#pragma unroll
        for (int j = 0; j < 8; ++j)
            nv[j] = sqrtf(xv[0][j]*xv[0][j] + xv[1][j]*xv[1][j] + xv[2][j]*xv[2][j] + EPS_C);
        stw(512 + l16 * 8, nv);
    }
    __syncthreads();   // drains DMAs (vmcnt) + ds_writes (lgkm): full x1 image ready

    // ---------------- GEMM1: wave w owns N-cols [w*64, w*64+64), ring-3 weight prefetch ----------------
    f32x4 acc[4][4];
#pragma unroll
    for (int mt = 0; mt < 4; ++mt)
#pragma unroll
        for (int n = 0; n < 4; ++n) acc[mt][n] = (f32x4){0.f, 0.f, 0.f, 0.f};

    {
        const bf16x8* wb = w1p + (size_t)(w * 4) * 64 + lane;
        auto LB1 = [&](bf16x8* B, int kt) {
#pragma unroll
            for (int n = 0; n < 4; ++n) B[n] = wb[(size_t)kt * 4096 + n * 64];
        };
        auto MM1 = [&](const bf16x8* B, int kt) {
            const unsigned short* ab = buf + kt * 2048 + lane * 8;
            __builtin_amdgcn_s_setprio(1);
#pragma unroll
            for (int mt = 0; mt < 4; ++mt) {
                const bf16x8 a = *reinterpret_cast<const bf16x8*>(ab + mt * 512);
#pragma unroll
                for (int n = 0; n < 4; ++n) acc[mt][n] = MFMA16(a, B[n], acc[mt][n]);
            }
            __builtin_amdgcn_s_setprio(0);
        };
        bf16x8 Bb[3][4];
        LB1(Bb[0], 0); LB1(Bb[1], 1);
#pragma unroll
        for (int kt = 0; kt < 36; ++kt) {
            if (kt + 2 < 36) LB1(Bb[(kt + 2) % 3], kt + 2);
            MM1(Bb[kt % 3], kt);
        }
    }
    __syncthreads();   // all x1 reads done; reuse buf kt 0..31 as h fragments

    // ---------------- bias + GELU -> h frag-major ----------------
    {
        float bv1[4];
#pragma unroll
        for (int n = 0; n < 4; ++n) bv1[n] = b1[w * 64 + n * 16 + lr];
#pragma unroll
        for (int n = 0; n < 4; ++n) {
            const int ktn = w * 2 + (n >> 1);
            const int sub = ((n & 1) * 2 + (lr >> 3)) * 128 + (lr & 7);
#pragma unroll
            for (int mt = 0; mt < 4; ++mt)
#pragma unroll
                for (int j = 0; j < 4; ++j)
                    buf[(ktn * 4 + mt) * 512 + sub + (lk * 4 + j) * 8] =
                        f2bf(gelu_f(acc[mt][n][j] + bv1[n]));
        }
    }
    __syncthreads();

    // ---------------- GEMM2: wave (mh = w>>3) x (g = w&7); nt = {g, g+8, g+16, g+24}, ring-3 ----------------
    const int mh = w >> 3;
    const int g  = w & 7;

    f32x4 acc2[2][4];
#pragma unroll
    for (int mtl = 0; mtl < 2; ++mtl)
#pragma unroll
        for (int p = 0; p < 4; ++p) acc2[mtl][p] = (f32x4){0.f, 0.f, 0.f, 0.f};

    {
        const bf16x8* wb2 = w2p + (size_t)g * 64 + lane;
        auto LB2 = [&](bf16x8* C, int kt2) {
#pragma unroll
            for (int p = 0; p < 4; ++p) C[p] = wb2[(size_t)kt2 * 2048 + p * 512];
        };
        auto MM2 = [&](const bf16x8* C, int kt2) {
            const unsigned short* ab = buf + kt2 * 2048 + lane * 8 + (mh * 2) * 512;
            __builtin_amdgcn_s_setprio(1);
#pragma unroll
            for (int mtl = 0; mtl < 2; ++mtl) {
                const bf16x8 a = *reinterpret_cast<const bf16x8*>(ab + mtl * 512);
#pragma unroll
                for (int p = 0; p < 4; ++p) acc2[mtl][p] = MFMA16(a, C[p], acc2[mtl][p]);
            }
            __builtin_amdgcn_s_setprio(0);
        };
        bf16x8 Cb[3][4];
        LB2(Cb[0], 0); LB2(Cb[1], 1);
#pragma unroll
        for (int kt2 = 0; kt2 < 32; ++kt2) {
            if (kt2 + 2 < 32) LB2(Cb[(kt2 + 2) % 3], kt2 + 2);
            MM2(Cb[kt2 % 3], kt2);
        }
    }

    // ---------------- epilogue: in-register rotation + store ----------------
    {
        float bv2[4];
#pragma unroll
        for (int p = 0; p < 4; ++p) bv2[p] = b2[p * 128 + g * 16 + lr];
        const int fcol = g * 16 + lr;
#pragma unroll
        for (int mtl = 0; mtl < 2; ++mtl) {
#pragma unroll
            for (int j = 0; j < 4; ++j) {
                const int rl = (mh * 2 + mtl) * 16 + lk * 4 + j;
                if (row0 + rl < nrows) {
                    const float* Rp = R_s + rl * 9;
                    const float y0 = acc2[mtl][0][j] + bv2[0];
                    const float y1 = acc2[mtl][1][j] + bv2[1];
                    const float y2 = acc2[mtl][2][j] + bv2[2];
                    const float y3 = acc2[mtl][3][j] + bv2[3];
                    float* op = out + (size_t)(row0 + rl) * 512 + fcol;
                    op[0]   = y0;
                    op[128] = Rp[0] * y1 + Rp[1] * y2 + Rp[2] * y3;
                    op[256] = Rp[3] * y1 + Rp[4] * y2 + Rp[5] * y3;
                    op[384] = Rp[6] * y1 + Rp[7] * y2 + Rp[8] * y3;
                }
            }
        }
    }
}

extern "C" void kernel_launch(void* const* d_in, const int* in_sizes, int n_in,
                              void* d_out, int out_size, void* d_ws, size_t ws_size,
                              hipStream_t stream) {
    const float* x     = (const float*)d_in[0];
    const float* rot   = (const float*)d_in[1];
    const float* extra = (const float*)d_in[2];
    const float* W1    = (const float*)d_in[3];
    const float* b1    = (const float*)d_in[4];
    const float* W2    = (const float*)d_in[5];
    const float* b2    = (const float*)d_in[6];
    float* out = (float*)d_out;

    const int nrows = in_sizes[0] / 512;
    const int nblk  = (nrows + BMA - 1) / BMA;

    // ws: W1 packed (2304 KB) | W2 packed (1024 KB) | prepack spill
    unsigned short* w1p = (unsigned short*)d_ws;
    unsigned short* w2p = (unsigned short*)((char*)d_ws + (size_t)2304 * 1024);
    char* pspill        = (char*)d_ws + (size_t)3328 * 1024;

    // prepack for block b lives at d_out + b*OUT_BLK_BYTES (read by block b before it
    // overwrites that region); blocks whose region would overflow d_out spill to ws.
    const long long out_bytes = (long long)out_size * 4;
    int spill_start = (int)((out_bytes - PREP_BYTES) / OUT_BLK_BYTES) + 1;
    if (spill_start > nblk) spill_start = nblk;
    if (spill_start < 0) spill_start = 0;

    const int totFrag = 3328 + nblk * 80;
    prep_kernel<<<(totFrag * 64 + 255) / 256, 256, 0, stream>>>(
        W1, W2, x, extra, w1p, w2p, (char*)d_out, pspill, nrows, nblk, spill_start);

    fused_kernel<<<nblk, 1024, 0, stream>>>(x, rot, b1, b2,
                                            (const bf16x8*)w1p, (const bf16x8*)w2p,
                                            (const char*)d_out, (const char*)pspill,
                                            out, nrows, spill_start);
}

// Round 6
// 562.804 us; speedup vs baseline: 1.0219x; 1.0219x over previous
//
#include <hip/hip_runtime.h>
#include <math.h>

#define HIDDEN   1024
#define IN_DIM   1152
#define OUT_D    512
#define EPS_C    1e-4f
#define BMA      64
#define OUT_BLK_BYTES 131072   // 64 rows * 512 f32
#define PREP_BYTES    81920    // 80 frags * 1024 B per block (x0: 16, extra: 64)

typedef __attribute__((ext_vector_type(8)))  __bf16 bf16x8;
typedef __attribute__((ext_vector_type(4)))  float  f32x4;
typedef __attribute__((ext_vector_type(16))) float  f32x16;

#define MFMA16(a, b, c) __builtin_amdgcn_mfma_f32_16x16x32_bf16(a, b, c, 0, 0, 0)
#define MFMA32(a, b, c) __builtin_amdgcn_mfma_f32_32x32x16_bf16(a, b, c, 0, 0, 0)

static __device__ __forceinline__ unsigned short f2bf(float f) {
    union { float f; unsigned u; } v; v.f = f;
    unsigned r = v.u + 0x7fffu + ((v.u >> 16) & 1u);
    return (unsigned short)(r >> 16);
}

static __device__ __forceinline__ uint4 pack8(const float* v) {
    uint4 p;
    p.x = (unsigned)f2bf(v[0]) | ((unsigned)f2bf(v[1]) << 16);
    p.y = (unsigned)f2bf(v[2]) | ((unsigned)f2bf(v[3]) << 16);
    p.z = (unsigned)f2bf(v[4]) | ((unsigned)f2bf(v[5]) << 16);
    p.w = (unsigned)f2bf(v[6]) | ((unsigned)f2bf(v[7]) << 16);
    return p;
}

// tanh-form GELU via sigmoid: g = v * sigmoid(c1*v + c3*v^3), max err ~1e-3
static __device__ __forceinline__ float gelu_f(float v) {
    const float t = -v * (1.5957691216f + 0.0713548163f * v * v);
    return v / (1.0f + __expf(t));
}

// ============ prep: pack W1 (32x32 B-frags, k-permuted), W2 (16x16 B-frags), per-block x0+extra ============
// 32x32x16 frag: lane holds elem[k = kt*16 + 8*(lane>>5) + i][col/row = tile*32 + (lane&31)], i=0..7.
// 16x16x32 frag: lane holds B[kt*32 + 8*(lane>>4) + i][nt*16 + (lane&15)], i=0..7.
// All frags stored as frag*512 + lane*8 ushorts (one dwordx4 per lane).
__global__ void prep_kernel(const float* __restrict__ W1, const float* __restrict__ W2,
                            const float* __restrict__ x, const float* __restrict__ extra,
                            unsigned short* __restrict__ w1p, unsigned short* __restrict__ w2p,
                            char* __restrict__ pmain, char* __restrict__ pspill,
                            int nrows, int nblk, int spill_start) {
    const int tid  = blockIdx.x * 256 + threadIdx.x;
    const int frag = tid >> 6;
    const int lane = tid & 63;
    if (frag < 2304) {
        // ---- W1: 32x32 layout, kt = frag>>5 (72), nt32 = frag&31 ----
        const int kt   = frag >> 5;
        const int nt32 = frag & 31;
        const int k0   = kt * 16 + ((lane >> 5) << 3);
        const int n    = nt32 * 32 + (lane & 31);
        float v[8];
#pragma unroll
        for (int i = 0; i < 8; ++i) {
            int kp = k0 + i, ko = kp;
            if (kp >= 128 && kp < 512) { const int q = kp - 128; ko = 128 + (q & 127) * 3 + (q >> 7); }
            v[i] = W1[(size_t)ko * 1024 + n];
        }
        *reinterpret_cast<uint4*>(w1p + (size_t)frag * 512 + lane * 8) = pack8(v);
    } else if (frag < 3328) {
        // ---- W2: 16x16 layout, fl = frag-2304, kt = fl>>5 (32), nt = fl&31 ----
        const int fl = frag - 2304;
        const int kt = fl >> 5;
        const int nt = fl & 31;
        const int k0 = kt * 32 + ((lane >> 4) << 3);
        const int n  = nt * 16 + (lane & 15);
        float v[8];
#pragma unroll
        for (int i = 0; i < 8; ++i) v[i] = W2[(size_t)(k0 + i) * 512 + n];
        *reinterpret_cast<uint4*>(w2p + (size_t)fl * 512 + lane * 8) = pack8(v);
    } else {
        // ---- per-block x0/extra prepack in 32x32 A-frag layout ----
        const int fp = frag - 3328;
        const int b  = fp / 80;
        if (b >= nblk) return;
        const int fl = fp - b * 80;
        const int g  = (fl < 16) ? fl : (fl - 16);
        const int row = b * 64 + (g & 1) * 32 + (lane & 31);
        const int col = (g >> 1) * 16 + ((lane >> 5) << 3);
        const float* src = (fl < 16) ? (x + (size_t)row * 512 + col)
                                     : (extra + (size_t)row * 512 + col);
        float v[8];
#pragma unroll
        for (int i = 0; i < 8; ++i) v[i] = 0.0f;
        if (row < nrows) {
            float4 lo = *reinterpret_cast<const float4*>(src);
            float4 hi = *reinterpret_cast<const float4*>(src + 4);
            v[0]=lo.x; v[1]=lo.y; v[2]=lo.z; v[3]=lo.w;
            v[4]=hi.x; v[5]=hi.y; v[6]=hi.z; v[7]=hi.w;
        }
        char* base = (b < spill_start) ? (pmain + (size_t)b * OUT_BLK_BYTES)
                                       : (pspill + (size_t)(b - spill_start) * PREP_BYTES);
        *reinterpret_cast<uint4*>(base + fl * 1024 + lane * 16) = pack8(v);
    }
}

// ===================== fused: DMA-stage + features + GEMM1(32x32) + GELU + GEMM2(16x16) + rotation =====================
__global__ __launch_bounds__(1024, 4)
void fused_kernel(const float* __restrict__ x, const float* __restrict__ rot,
                  const float* __restrict__ b1, const float* __restrict__ b2,
                  const char* __restrict__ w1pc, const bf16x8* __restrict__ w2p,
                  const char* __restrict__ pmain, const char* __restrict__ pspill,
                  float* __restrict__ out, int nrows, int spill_start) {
    // x1 A-frag image (32x32 layout): 72 kt x 2 mt32 x 1KB = 147456 B
    // h-frag image (16x16 layout): 32 ktn x 4 mt16 x 1KB = 131072 B  [aliases]
    __shared__ __align__(16) unsigned short buf[72 * 2 * 512];
    __shared__ float R_s[BMA * 9];

    const int tid  = threadIdx.x;
    const int bid  = blockIdx.x;
    const int row0 = bid * BMA;
    const int w    = tid >> 6;   // wave 0..15
    const int lane = tid & 63;

    // ---------------- phase 0: issue all x0/extra DMAs (global -> LDS direct) ----------------
    {
        const char* pbase = (bid < spill_start) ? (pmain + (size_t)bid * OUT_BLK_BYTES)
                                                : (pspill + (size_t)(bid - spill_start) * PREP_BYTES);
#pragma unroll
        for (int q = 0; q < 5; ++q) {
            const int fl = w * 5 + q;                     // 0..79
            const int F  = (fl < 16) ? fl : fl + 64;      // x0 -> frags 0..15 (kt 0..7), extra -> 80..143 (kt 40..71)
            __builtin_amdgcn_global_load_lds(
                (const __attribute__((address_space(1))) unsigned int*)(pbase + fl * 1024 + lane * 16),
                (__attribute__((address_space(3))) unsigned int*)(buf + F * 512),
                16, 0, 0);
        }
    }

    // ---------------- phase 1: vec_local (k-major) + vec_norm -> kt 8..39 ----------------
    {
        const int m    = tid >> 4;       // row 0..63
        const int l16  = tid & 15;
        const int mt32 = m >> 5;
        const int f0   = l16 * 8;
        int i = row0 + m; if (i > nrows - 1) i = nrows - 1;
        float r[9];
#pragma unroll
        for (int q = 0; q < 9; ++q) r[q] = rot[(size_t)i * 9 + q];
        if (l16 < 9) R_s[m * 9 + l16] = r[l16];
        const float* xp = x + (size_t)i * 512 + f0;
        float xv[3][8];
#pragma unroll
        for (int c = 0; c < 3; ++c) {
            float4 lo = *reinterpret_cast<const float4*>(xp + (c + 1) * 128);
            float4 hi = *reinterpret_cast<const float4*>(xp + (c + 1) * 128 + 4);
            xv[c][0]=lo.x; xv[c][1]=lo.y; xv[c][2]=lo.z; xv[c][3]=lo.w;
            xv[c][4]=hi.x; xv[c][5]=hi.y; xv[c][6]=hi.z; xv[c][7]=hi.w;
        }
        // 16B store of 8 bf16 at packed-k k0v (mult of 8): frag (k0v>>4, mt32), lane32 = (m&31) + 32*((k0v>>3)&1)
        auto stw = [&](int k0v, const float* v8) {
            *reinterpret_cast<uint4*>(buf + ((k0v >> 4) * 2 + mt32) * 512 +
                                      ((m & 31) + 32 * ((k0v >> 3) & 1)) * 8) = pack8(v8);
        };
#pragma unroll
        for (int kk = 0; kk < 3; ++kk) {
            float vl[8];
#pragma unroll
            for (int j = 0; j < 8; ++j)
                vl[j] = xv[0][j] * r[kk] + xv[1][j] * r[3 + kk] + xv[2][j] * r[6 + kk];
            stw(128 + kk * 128 + f0, vl);
        }
        float nv[8];
#pragma unroll
        for (int j = 0; j < 8; ++j)
            nv[j] = sqrtf(xv[0][j]*xv[0][j] + xv[1][j]*xv[1][j] + xv[2][j]*xv[2][j] + EPS_C);
        stw(512 + f0, nv);
    }
    __syncthreads();   // drains DMAs + ds_writes: full x1 image ready

    // ---------------- GEMM1 (32x32x16): wave w owns col-tiles {2w, 2w+1}; static ring-3 ----------------
    const float bw1a = b1[(2 * w)     * 32 + (lane & 31)];
    const float bw1b = b1[(2 * w + 1) * 32 + (lane & 31)];

    f32x16 acc00, acc01, acc10, acc11;
#pragma unroll
    for (int z = 0; z < 16; ++z) { acc00[z] = 0.f; acc01[z] = 0.f; acc10[z] = 0.f; acc11[z] = 0.f; }

    {
        const char* wbase = w1pc + ((size_t)(2 * w) * 1024) + lane * 16;   // frag (kt,nt) at (kt*32+nt)*1024 B
        auto LB = [&](bf16x8& B0, bf16x8& B1, int kt) {
            B0 = *reinterpret_cast<const bf16x8*>(wbase + (size_t)kt * 32768);
            B1 = *reinterpret_cast<const bf16x8*>(wbase + (size_t)kt * 32768 + 1024);
        };
        auto MM = [&](const bf16x8 B0, const bf16x8 B1, int kt) {
            const unsigned short* ap = buf + kt * 1024 + lane * 8;
            const bf16x8 A0 = *reinterpret_cast<const bf16x8*>(ap);
            const bf16x8 A1 = *reinterpret_cast<const bf16x8*>(ap + 512);
            __builtin_amdgcn_s_setprio(1);
            acc00 = MFMA32(A0, B0, acc00);
            acc01 = MFMA32(A0, B1, acc01);
            acc10 = MFMA32(A1, B0, acc10);
            acc11 = MFMA32(A1, B1, acc11);
            __builtin_amdgcn_s_setprio(0);
        };
        bf16x8 Ba0, Ba1, Bb0, Bb1, Bc0, Bc1;
        LB(Ba0, Ba1, 0); LB(Bb0, Bb1, 1);
#pragma unroll
        for (int kt = 0; kt < 72; kt += 3) {
            LB(Bc0, Bc1, kt + 2);
            MM(Ba0, Ba1, kt);
            if (kt + 3 < 72) LB(Ba0, Ba1, kt + 3);
            MM(Bb0, Bb1, kt + 1);
            if (kt + 4 < 72) LB(Bb0, Bb1, kt + 4);
            MM(Bc0, Bc1, kt + 2);
        }
    }
    __syncthreads();   // all x1 reads done; reuse buf[0..131072) as h fragments (16x16 layout)

    // ---------------- bias + GELU -> h frag-major (16x16 A-layout) ----------------
    {
        const int hi5 = lane >> 5;          // C row group
        const int cz  = (lane & 31) >> 3;   // (col&31)>>3
        const int i7  = lane & 7;           // col&7
        auto GEL = [&](const f32x16& A, int mtl, int ntl, float bb) {
            const int ktn = 2 * w + ntl;
#pragma unroll
            for (int reg = 0; reg < 16; ++reg) {
                const int mt16 = mtl * 2 + (reg >> 3);
                const int rlo  = (reg & 3) + 8 * ((reg >> 2) & 1) + 4 * hi5;
                buf[(ktn * 4 + mt16) * 512 + (rlo + 16 * cz) * 8 + i7] =
                    f2bf(gelu_f(A[reg] + bb));
            }
        };
        GEL(acc00, 0, 0, bw1a);
        GEL(acc01, 0, 1, bw1b);
        GEL(acc10, 1, 0, bw1a);
        GEL(acc11, 1, 1, bw1b);
    }
    __syncthreads();

    // ---------------- GEMM2 (16x16x32): wave (mh = w>>3) x (g = w&7); nt = {g, g+8, g+16, g+24}; static dbuf-2 ----------------
    const int mh = w >> 3;
    const int g  = w & 7;
    const int lr = lane & 15;
    const int lk = lane >> 4;

    f32x4 acc2[2][4];
#pragma unroll
    for (int mtl = 0; mtl < 2; ++mtl)
#pragma unroll
        for (int p = 0; p < 4; ++p) acc2[mtl][p] = (f32x4){0.f, 0.f, 0.f, 0.f};

    {
        const bf16x8* wb2 = w2p + (size_t)g * 64 + lane;
        auto LB2 = [&](bf16x8* C, int kt2) {
#pragma unroll
            for (int p = 0; p < 4; ++p) C[p] = wb2[(size_t)kt2 * 2048 + p * 512];
        };
        auto MM2 = [&](const bf16x8* C, int kt2) {
            const unsigned short* ab = buf + kt2 * 2048 + (mh * 2) * 512 + lane * 8;
            const bf16x8 a0 = *reinterpret_cast<const bf16x8*>(ab);
            const bf16x8 a1 = *reinterpret_cast<const bf16x8*>(ab + 512);
            __builtin_amdgcn_s_setprio(1);
#pragma unroll
            for (int p = 0; p < 4; ++p) {
                acc2[0][p] = MFMA16(a0, C[p], acc2[0][p]);
                acc2[1][p] = MFMA16(a1, C[p], acc2[1][p]);
            }
            __builtin_amdgcn_s_setprio(0);
        };
        bf16x8 Ca[4], Cb[4];
        LB2(Ca, 0);
#pragma unroll
        for (int kt2 = 0; kt2 < 32; kt2 += 2) {
            if (kt2 + 1 < 32) LB2(Cb, kt2 + 1);
            MM2(Ca, kt2);
            if (kt2 + 2 < 32) LB2(Ca, kt2 + 2);
            if (kt2 + 1 < 32) MM2(Cb, kt2 + 1);
        }
    }

    // ---------------- epilogue: in-register rotation + store ----------------
    {
        float bv2[4];
#pragma unroll
        for (int p = 0; p < 4; ++p) bv2[p] = b2[p * 128 + g * 16 + lr];
        const int fcol = g * 16 + lr;
#pragma unroll
        for (int mtl = 0; mtl < 2; ++mtl) {
#pragma unroll
            for (int j = 0; j < 4; ++j) {
                const int rl = (mh * 2 + mtl) * 16 + lk * 4 + j;
                if (row0 + rl < nrows) {
                    const float* Rp = R_s + rl * 9;
                    const float y0 = acc2[mtl][0][j] + bv2[0];
                    const float y1 = acc2[mtl][1][j] + bv2[1];
                    const float y2 = acc2[mtl][2][j] + bv2[2];
                    const float y3 = acc2[mtl][3][j] + bv2[3];
                    float* op = out + (size_t)(row0 + rl) * 512 + fcol;
                    op[0]   = y0;
                    op[128] = Rp[0] * y1 + Rp[1] * y2 + Rp[2] * y3;
                    op[256] = Rp[3] * y1 + Rp[4] * y2 + Rp[5] * y3;
                    op[384] = Rp[6] * y1 + Rp[7] * y2 + Rp[8] * y3;
                }
            }
        }
    }
}

extern "C" void kernel_launch(void* const* d_in, const int* in_sizes, int n_in,
                              void* d_out, int out_size, void* d_ws, size_t ws_size,
                              hipStream_t stream) {
    const float* x     = (const float*)d_in[0];
    const float* rot   = (const float*)d_in[1];
    const float* extra = (const float*)d_in[2];
    const float* W1    = (const float*)d_in[3];
    const float* b1    = (const float*)d_in[4];
    const float* W2    = (const float*)d_in[5];
    const float* b2    = (const float*)d_in[6];
    float* out = (float*)d_out;

    const int nrows = in_sizes[0] / 512;
    const int nblk  = (nrows + BMA - 1) / BMA;

    // ws: W1 packed (2304 KB) | W2 packed (1024 KB) | prepack spill
    unsigned short* w1p = (unsigned short*)d_ws;
    unsigned short* w2p = (unsigned short*)((char*)d_ws + (size_t)2304 * 1024);
    char* pspill        = (char*)d_ws + (size_t)3328 * 1024;

    // prepack for block b lives at d_out + b*OUT_BLK_BYTES (read by block b before it
    // overwrites that region); blocks whose region would overflow d_out spill to ws.
    const long long out_bytes = (long long)out_size * 4;
    int spill_start = (int)((out_bytes - PREP_BYTES) / OUT_BLK_BYTES) + 1;
    if (spill_start > nblk) spill_start = nblk;
    if (spill_start < 0) spill_start = 0;

    const int totFrag = 3328 + nblk * 80;
    prep_kernel<<<(totFrag * 64 + 255) / 256, 256, 0, stream>>>(
        W1, W2, x, extra, w1p, w2p, (char*)d_out, pspill, nrows, nblk, spill_start);

    fused_kernel<<<nblk, 1024, 0, stream>>>(x, rot, b1, b2,
                                            (const char*)w1p, (const bf16x8*)w2p,
                                            (const char*)d_out, (const char*)pspill,
                                            out, nrows, spill_start);
}

// Round 7
// 548.038 us; speedup vs baseline: 1.0494x; 1.0269x over previous
//
#include <hip/hip_runtime.h>
#include <math.h>

#define HIDDEN   1024
#define IN_DIM   1152
#define OUT_D    512
#define EPS_C    1e-4f
#define BMA      64

typedef __attribute__((ext_vector_type(8)))  __bf16 bf16x8;
typedef __attribute__((ext_vector_type(4)))  float  f32x4;
typedef __attribute__((ext_vector_type(16))) float  f32x16;

#define MFMA16(a, b, c) __builtin_amdgcn_mfma_f32_16x16x32_bf16(a, b, c, 0, 0, 0)
#define MFMA32(a, b, c) __builtin_amdgcn_mfma_f32_32x32x16_bf16(a, b, c, 0, 0, 0)

static __device__ __forceinline__ unsigned short f2bf(float f) {
    union { float f; unsigned u; } v; v.f = f;
    unsigned r = v.u + 0x7fffu + ((v.u >> 16) & 1u);
    return (unsigned short)(r >> 16);
}

static __device__ __forceinline__ uint4 pack8(const float* v) {
    uint4 p;
    p.x = (unsigned)f2bf(v[0]) | ((unsigned)f2bf(v[1]) << 16);
    p.y = (unsigned)f2bf(v[2]) | ((unsigned)f2bf(v[3]) << 16);
    p.z = (unsigned)f2bf(v[4]) | ((unsigned)f2bf(v[5]) << 16);
    p.w = (unsigned)f2bf(v[6]) | ((unsigned)f2bf(v[7]) << 16);
    return p;
}

static __device__ __forceinline__ uint4 pack8v(f32x4 lo, f32x4 hi) {
    uint4 p;
    p.x = (unsigned)f2bf(lo[0]) | ((unsigned)f2bf(lo[1]) << 16);
    p.y = (unsigned)f2bf(lo[2]) | ((unsigned)f2bf(lo[3]) << 16);
    p.z = (unsigned)f2bf(hi[0]) | ((unsigned)f2bf(hi[1]) << 16);
    p.w = (unsigned)f2bf(hi[2]) | ((unsigned)f2bf(hi[3]) << 16);
    return p;
}

// tanh-form GELU via sigmoid: g = v * sigmoid(c1*v + c3*v^3), max err ~1e-3
static __device__ __forceinline__ float gelu_f(float v) {
    const float t = -v * (1.5957691216f + 0.0713548163f * v * v);
    return v / (1.0f + __expf(t));
}

// ============ prep: pack W1 (32x32 B-frags, k-permuted rows) and W2 (16x16 B-frags) ============
// 32x32x16 frag: lane holds B[k = kt*16 + 8*(lane>>5) + i][n = nt32*32 + (lane&31)], i=0..7.
// 16x16x32 frag: lane holds B[kt*32 + 8*(lane>>4) + i][nt*16 + (lane&15)], i=0..7.
// All frags stored as frag*512 + lane*8 ushorts (one dwordx4 per lane).
// W1 row perm: packed row kp in [128,512) reads orig row 128 + ((kp-128)&127)*3 + ((kp-128)>>7).
__global__ void prep_kernel(const float* __restrict__ W1, const float* __restrict__ W2,
                            unsigned short* __restrict__ w1p, unsigned short* __restrict__ w2p) {
    const int tid  = blockIdx.x * 256 + threadIdx.x;
    const int frag = tid >> 6;
    if (frag >= 3328) return;
    const int lane = tid & 63;
    if (frag < 2304) {
        const int kt   = frag >> 5;
        const int nt32 = frag & 31;
        const int k0   = kt * 16 + ((lane >> 5) << 3);
        const int n    = nt32 * 32 + (lane & 31);
        float v[8];
#pragma unroll
        for (int i = 0; i < 8; ++i) {
            int kp = k0 + i, ko = kp;
            if (kp >= 128 && kp < 512) { const int q = kp - 128; ko = 128 + (q & 127) * 3 + (q >> 7); }
            v[i] = W1[(size_t)ko * 1024 + n];
        }
        *reinterpret_cast<uint4*>(w1p + (size_t)frag * 512 + lane * 8) = pack8(v);
    } else {
        const int fl = frag - 2304;
        const int kt = fl >> 5;
        const int nt = fl & 31;
        const int k0 = kt * 32 + ((lane >> 4) << 3);
        const int n  = nt * 16 + (lane & 15);
        float v[8];
#pragma unroll
        for (int i = 0; i < 8; ++i) v[i] = W2[(size_t)(k0 + i) * 512 + n];
        *reinterpret_cast<uint4*>(w2p + (size_t)fl * 512 + lane * 8) = pack8(v);
    }
}

// ===================== fused: nt-stream features + GEMM1(32x32) + GELU + GEMM2(16x16) + rotation =====================
__global__ __launch_bounds__(1024, 4)
void fused_kernel(const float* __restrict__ x, const float* __restrict__ rot,
                  const float* __restrict__ extra,
                  const float* __restrict__ b1, const float* __restrict__ b2,
                  const char* __restrict__ w1pc, const bf16x8* __restrict__ w2p,
                  float* __restrict__ out, int nrows) {
    // x1 A-frag image (32x32 layout): 72 kt x 2 mt32 x 1KB = 147456 B
    // h-frag image (16x16 layout): 32 ktn x 4 mt16 x 1KB = 131072 B  [aliases]
    __shared__ __align__(16) unsigned short buf[72 * 2 * 512];
    __shared__ float R_s[BMA * 9];

    const int tid  = threadIdx.x;
    const int row0 = blockIdx.x * BMA;
    const int w    = tid >> 6;   // wave 0..15
    const int lane = tid & 63;

    // ---------------- phase 1: build full x1 image from nt-streamed x/extra ----------------
    {
        const int m    = tid >> 4;       // row 0..63
        const int l16  = tid & 15;
        const int mt32 = m >> 5;
        const int f0   = l16 * 8;
        int i = row0 + m; if (i > nrows - 1) i = nrows - 1;

        // issue all streaming loads up front (16 x dwordx4, non-temporal: keep L2 for weights)
        const float* xp = x + (size_t)i * 512 + f0;
        const float* ep = extra + (size_t)i * 512 + l16 * 32;
        f32x4 xl[8], el[8];
#pragma unroll
        for (int c = 0; c < 4; ++c) {
            xl[2 * c]     = __builtin_nontemporal_load(reinterpret_cast<const f32x4*>(xp + c * 128));
            xl[2 * c + 1] = __builtin_nontemporal_load(reinterpret_cast<const f32x4*>(xp + c * 128 + 4));
        }
#pragma unroll
        for (int q = 0; q < 8; ++q)
            el[q] = __builtin_nontemporal_load(reinterpret_cast<const f32x4*>(ep + q * 4));

        float r[9];
#pragma unroll
        for (int q = 0; q < 9; ++q) r[q] = rot[(size_t)i * 9 + q];
        if (l16 < 9) R_s[m * 9 + l16] = r[l16];

        // 16B store of 8 bf16 at packed-k k0v (mult of 8): frag (k0v>>4, mt32), lane32 = (m&31)+32*((k0v>>3)&1)
        auto stw = [&](int k0v, uint4 pv) {
            *reinterpret_cast<uint4*>(buf + ((k0v >> 4) * 2 + mt32) * 512 +
                                      ((m & 31) + 32 * ((k0v >> 3) & 1)) * 8) = pv;
        };

        stw(f0, pack8v(xl[0], xl[1]));                     // x[:,0] -> packed k [0,128)
#pragma unroll
        for (int kk = 0; kk < 3; ++kk) {                   // vec_local (k-major) -> k [128,512)
            float vl[8];
#pragma unroll
            for (int j = 0; j < 8; ++j) {
                const float a = xl[2 + (j >> 2)][j & 3], b = xl[4 + (j >> 2)][j & 3], c = xl[6 + (j >> 2)][j & 3];
                vl[j] = a * r[kk] + b * r[3 + kk] + c * r[6 + kk];
            }
            stw(128 + kk * 128 + f0, pack8(vl));
        }
        {
            float nv[8];                                   // vec_norm -> k [512,640)
#pragma unroll
            for (int j = 0; j < 8; ++j) {
                const float a = xl[2 + (j >> 2)][j & 3], b = xl[4 + (j >> 2)][j & 3], c = xl[6 + (j >> 2)][j & 3];
                nv[j] = sqrtf(a * a + b * b + c * c + EPS_C);
            }
            stw(512 + f0, pack8(nv));
        }
#pragma unroll
        for (int q = 0; q < 4; ++q)                        // extra -> k [640,1152)
            stw(640 + l16 * 32 + q * 8, pack8v(el[2 * q], el[2 * q + 1]));
    }
    __syncthreads();   // full x1 image ready

    // ---------------- GEMM1 (32x32x16): wave w owns col-tiles {2w, 2w+1}; static ring-3 ----------------
    const float bw1a = b1[(2 * w)     * 32 + (lane & 31)];
    const float bw1b = b1[(2 * w + 1) * 32 + (lane & 31)];

    f32x16 acc00, acc01, acc10, acc11;
#pragma unroll
    for (int z = 0; z < 16; ++z) { acc00[z] = 0.f; acc01[z] = 0.f; acc10[z] = 0.f; acc11[z] = 0.f; }

    {
        const char* wbase = w1pc + ((size_t)(2 * w) * 1024) + lane * 16;   // frag (kt,nt) at (kt*32+nt)*1024 B
        auto LB = [&](bf16x8& B0, bf16x8& B1, int kt) {
            B0 = *reinterpret_cast<const bf16x8*>(wbase + (size_t)kt * 32768);
            B1 = *reinterpret_cast<const bf16x8*>(wbase + (size_t)kt * 32768 + 1024);
        };
        auto MM = [&](const bf16x8 B0, const bf16x8 B1, int kt) {
            const unsigned short* ap = buf + kt * 1024 + lane * 8;
            const bf16x8 A0 = *reinterpret_cast<const bf16x8*>(ap);
            const bf16x8 A1 = *reinterpret_cast<const bf16x8*>(ap + 512);
            __builtin_amdgcn_s_setprio(1);
            acc00 = MFMA32(A0, B0, acc00);
            acc01 = MFMA32(A0, B1, acc01);
            acc10 = MFMA32(A1, B0, acc10);
            acc11 = MFMA32(A1, B1, acc11);
            __builtin_amdgcn_s_setprio(0);
        };
        bf16x8 Ba0, Ba1, Bb0, Bb1, Bc0, Bc1;
        LB(Ba0, Ba1, 0); LB(Bb0, Bb1, 1);
#pragma unroll
        for (int kt = 0; kt < 72; kt += 3) {
            LB(Bc0, Bc1, kt + 2);
            MM(Ba0, Ba1, kt);
            if (kt + 3 < 72) LB(Ba0, Ba1, kt + 3);
            MM(Bb0, Bb1, kt + 1);
            if (kt + 4 < 72) LB(Bb0, Bb1, kt + 4);
            MM(Bc0, Bc1, kt + 2);
        }
    }
    __syncthreads();   // all x1 reads done; reuse buf[0..131072) as h fragments (16x16 layout)

    // ---------------- bias + GELU -> h frag-major (16x16 A-layout) ----------------
    {
        const int hi5 = lane >> 5;          // C row group
        const int cz  = (lane & 31) >> 3;   // (col&31)>>3
        const int i7  = lane & 7;           // col&7
        auto GEL = [&](const f32x16& A, int mtl, int ntl, float bb) {
            const int ktn = 2 * w + ntl;
#pragma unroll
            for (int reg = 0; reg < 16; ++reg) {
                const int mt16 = mtl * 2 + (reg >> 3);
                const int rlo  = (reg & 3) + 8 * ((reg >> 2) & 1) + 4 * hi5;
                buf[(ktn * 4 + mt16) * 512 + (rlo + 16 * cz) * 8 + i7] =
                    f2bf(gelu_f(A[reg] + bb));
            }
        };
        GEL(acc00, 0, 0, bw1a);
        GEL(acc01, 0, 1, bw1b);
        GEL(acc10, 1, 0, bw1a);
        GEL(acc11, 1, 1, bw1b);
    }
    __syncthreads();

    // ---------------- GEMM2 (16x16x32): wave (mh = w>>3) x (g = w&7); nt = {g, g+8, g+16, g+24}; static dbuf-2 ----------------
    const int mh = w >> 3;
    const int g  = w & 7;
    const int lr = lane & 15;
    const int lk = lane >> 4;

    f32x4 acc2[2][4];
#pragma unroll
    for (int mtl = 0; mtl < 2; ++mtl)
#pragma unroll
        for (int p = 0; p < 4; ++p) acc2[mtl][p] = (f32x4){0.f, 0.f, 0.f, 0.f};

    {
        const bf16x8* wb2 = w2p + (size_t)g * 64 + lane;
        auto LB2 = [&](bf16x8* C, int kt2) {
#pragma unroll
            for (int p = 0; p < 4; ++p) C[p] = wb2[(size_t)kt2 * 2048 + p * 512];
        };
        auto MM2 = [&](const bf16x8* C, int kt2) {
            const unsigned short* ab = buf + kt2 * 2048 + (mh * 2) * 512 + lane * 8;
            const bf16x8 a0 = *reinterpret_cast<const bf16x8*>(ab);
            const bf16x8 a1 = *reinterpret_cast<const bf16x8*>(ab + 512);
            __builtin_amdgcn_s_setprio(1);
#pragma unroll
            for (int p = 0; p < 4; ++p) {
                acc2[0][p] = MFMA16(a0, C[p], acc2[0][p]);
                acc2[1][p] = MFMA16(a1, C[p], acc2[1][p]);
            }
            __builtin_amdgcn_s_setprio(0);
        };
        bf16x8 Ca[4], Cb[4];
        LB2(Ca, 0);
#pragma unroll
        for (int kt2 = 0; kt2 < 32; kt2 += 2) {
            if (kt2 + 1 < 32) LB2(Cb, kt2 + 1);
            MM2(Ca, kt2);
            if (kt2 + 2 < 32) LB2(Ca, kt2 + 2);
            if (kt2 + 1 < 32) MM2(Cb, kt2 + 1);
        }
    }

    // ---------------- epilogue: in-register rotation + nt store ----------------
    {
        float bv2[4];
#pragma unroll
        for (int p = 0; p < 4; ++p) bv2[p] = b2[p * 128 + g * 16 + lr];
        const int fcol = g * 16 + lr;
#pragma unroll
        for (int mtl = 0; mtl < 2; ++mtl) {
#pragma unroll
            for (int j = 0; j < 4; ++j) {
                const int rl = (mh * 2 + mtl) * 16 + lk * 4 + j;
                if (row0 + rl < nrows) {
                    const float* Rp = R_s + rl * 9;
                    const float y0 = acc2[mtl][0][j] + bv2[0];
                    const float y1 = acc2[mtl][1][j] + bv2[1];
                    const float y2 = acc2[mtl][2][j] + bv2[2];
                    const float y3 = acc2[mtl][3][j] + bv2[3];
                    float* op = out + (size_t)(row0 + rl) * 512 + fcol;
                    __builtin_nontemporal_store(y0, op);
                    __builtin_nontemporal_store(Rp[0] * y1 + Rp[1] * y2 + Rp[2] * y3, op + 128);
                    __builtin_nontemporal_store(Rp[3] * y1 + Rp[4] * y2 + Rp[5] * y3, op + 256);
                    __builtin_nontemporal_store(Rp[6] * y1 + Rp[7] * y2 + Rp[8] * y3, op + 384);
                }
            }
        }
    }
}

extern "C" void kernel_launch(void* const* d_in, const int* in_sizes, int n_in,
                              void* d_out, int out_size, void* d_ws, size_t ws_size,
                              hipStream_t stream) {
    const float* x     = (const float*)d_in[0];
    const float* rot   = (const float*)d_in[1];
    const float* extra = (const float*)d_in[2];
    const float* W1    = (const float*)d_in[3];
    const float* b1    = (const float*)d_in[4];
    const float* W2    = (const float*)d_in[5];
    const float* b2    = (const float*)d_in[6];
    float* out = (float*)d_out;

    const int nrows = in_sizes[0] / 512;
    const int nblk  = (nrows + BMA - 1) / BMA;

    // ws: W1 packed (2304 KB) | W2 packed (1024 KB)
    unsigned short* w1p = (unsigned short*)d_ws;
    unsigned short* w2p = (unsigned short*)((char*)d_ws + (size_t)2304 * 1024);

    prep_kernel<<<(3328 * 64 + 255) / 256, 256, 0, stream>>>(W1, W2, w1p, w2p);

    fused_kernel<<<nblk, 1024, 0, stream>>>(x, rot, extra, b1, b2,
                                            (const char*)w1p, (const bf16x8*)w2p,
                                            out, nrows);
}

// Round 10
// 518.354 us; speedup vs baseline: 1.1095x; 1.0573x over previous
//
#include <hip/hip_runtime.h>
#include <math.h>

#define HIDDEN   1024
#define IN_DIM   1152
#define OUT_D    512
#define EPS_C    1e-4f
#define BMA      64

typedef __attribute__((ext_vector_type(8)))  __bf16 bf16x8;
typedef __attribute__((ext_vector_type(4)))  float  f32x4;
typedef __attribute__((ext_vector_type(16))) float  f32x16;

#define MFMA16(a, b, c) __builtin_amdgcn_mfma_f32_16x16x32_bf16(a, b, c, 0, 0, 0)
#define MFMA32(a, b, c) __builtin_amdgcn_mfma_f32_32x32x16_bf16(a, b, c, 0, 0, 0)

// packed bf16 convert: D[15:0]=bf16(a), D[31:16]=bf16(b), RNE (gfx950 HW op)
static __device__ __forceinline__ unsigned cvtpk(float a, float b) {
    unsigned r;
    asm("v_cvt_pk_bf16_f32 %0, %1, %2" : "=v"(r) : "v"(a), "v"(b));
    return r;
}

static __device__ __forceinline__ uint4 pack8(const float* v) {
    uint4 p;
    p.x = cvtpk(v[0], v[1]);
    p.y = cvtpk(v[2], v[3]);
    p.z = cvtpk(v[4], v[5]);
    p.w = cvtpk(v[6], v[7]);
    return p;
}

static __device__ __forceinline__ uint4 pack8v(f32x4 lo, f32x4 hi) {
    uint4 p;
    p.x = cvtpk(lo[0], lo[1]);
    p.y = cvtpk(lo[2], lo[3]);
    p.z = cvtpk(hi[0], hi[1]);
    p.w = cvtpk(hi[2], hi[3]);
    return p;
}

// tanh-form GELU via sigmoid: g = v * sigmoid(c1*v + c3*v^3), max err ~1e-3
static __device__ __forceinline__ float gelu_f(float v) {
    const float t = -v * (1.5957691216f + 0.0713548163f * v * v);
    return v / (1.0f + __expf(t));
}

// ============ prep: pack W1 (32x32 B-frags, k-permuted rows) and W2 (16x16 B-frags) ============
// 32x32x16 frag: lane holds B[k = kt*16 + 8*(lane>>5) + i][n = nt32*32 + (lane&31)], i=0..7.
// 16x16x32 frag: lane holds B[kt*32 + 8*(lane>>4) + i][nt*16 + (lane&15)], i=0..7.
// All frags stored as frag*512 + lane*8 ushorts (one dwordx4 per lane).
// W1 row perm: packed row kp in [128,512) reads orig row 128 + ((kp-128)&127)*3 + ((kp-128)>>7).
__global__ void prep_kernel(const float* __restrict__ W1, const float* __restrict__ W2,
                            unsigned short* __restrict__ w1p, unsigned short* __restrict__ w2p) {
    const int tid  = blockIdx.x * 256 + threadIdx.x;
    const int frag = tid >> 6;
    if (frag >= 3328) return;
    const int lane = tid & 63;
    if (frag < 2304) {
        const int kt   = frag >> 5;
        const int nt32 = frag & 31;
        const int k0   = kt * 16 + ((lane >> 5) << 3);
        const int n    = nt32 * 32 + (lane & 31);
        float v[8];
#pragma unroll
        for (int i = 0; i < 8; ++i) {
            int kp = k0 + i, ko = kp;
            if (kp >= 128 && kp < 512) { const int q = kp - 128; ko = 128 + (q & 127) * 3 + (q >> 7); }
            v[i] = W1[(size_t)ko * 1024 + n];
        }
        *reinterpret_cast<uint4*>(w1p + (size_t)frag * 512 + lane * 8) = pack8(v);
    } else {
        const int fl = frag - 2304;
        const int kt = fl >> 5;
        const int nt = fl & 31;
        const int k0 = kt * 32 + ((lane >> 4) << 3);
        const int n  = nt * 16 + (lane & 15);
        float v[8];
#pragma unroll
        for (int i = 0; i < 8; ++i) v[i] = W2[(size_t)(k0 + i) * 512 + n];
        *reinterpret_cast<uint4*>(w2p + (size_t)fl * 512 + lane * 8) = pack8(v);
    }
}

// ===================== fused: features + GEMM1(32x32) + GELU + GEMM2(16x16) + rotation =====================
__global__ __launch_bounds__(1024, 4)
void fused_kernel(const float* __restrict__ x, const float* __restrict__ rot,
                  const float* __restrict__ extra,
                  const float* __restrict__ b1, const float* __restrict__ b2,
                  const char* __restrict__ w1pc, const bf16x8* __restrict__ w2p,
                  float* __restrict__ out, int nrows) {
    // x1 A-frag image (32x32 layout): 72 kt x 2 mt32 x 1KB = 147456 B
    // h-frag image (16x16 layout): 32 ktn x 4 mt16 x 1KB = 131072 B  [aliases]
    __shared__ __align__(16) unsigned short buf[72 * 2 * 512];
    __shared__ float R_s[BMA * 9];

    const int tid  = threadIdx.x;
    const int row0 = blockIdx.x * BMA;
    const int w    = tid >> 6;   // wave 0..15
    const int lane = tid & 63;

    // ---------------- phase 1: build full x1 image from x/extra ----------------
    {
        const int m    = tid >> 4;       // row 0..63
        const int l16  = tid & 15;
        const int mt32 = m >> 5;
        const int f0   = l16 * 8;
        int i = row0 + m; if (i > nrows - 1) i = nrows - 1;

        const float* xp = x + (size_t)i * 512 + f0;
        const float* ep = extra + (size_t)i * 512 + l16 * 32;
        f32x4 xl[8], el[8];
#pragma unroll
        for (int c = 0; c < 4; ++c) {
            xl[2 * c]     = *reinterpret_cast<const f32x4*>(xp + c * 128);
            xl[2 * c + 1] = *reinterpret_cast<const f32x4*>(xp + c * 128 + 4);
        }
#pragma unroll
        for (int q = 0; q < 8; ++q)
            el[q] = *reinterpret_cast<const f32x4*>(ep + q * 4);

        float r[9];
#pragma unroll
        for (int q = 0; q < 9; ++q) r[q] = rot[(size_t)i * 9 + q];
        if (l16 < 9) R_s[m * 9 + l16] = r[l16];

        // 16B store of 8 bf16 at packed-k k0v (mult of 8): frag (k0v>>4, mt32), lane32 = (m&31)+32*((k0v>>3)&1)
        auto stw = [&](int k0v, uint4 pv) {
            *reinterpret_cast<uint4*>(buf + ((k0v >> 4) * 2 + mt32) * 512 +
                                      ((m & 31) + 32 * ((k0v >> 3) & 1)) * 8) = pv;
        };

        stw(f0, pack8v(xl[0], xl[1]));                     // x[:,0] -> packed k [0,128)
#pragma unroll
        for (int kk = 0; kk < 3; ++kk) {                   // vec_local (k-major) -> k [128,512)
            float vl[8];
#pragma unroll
            for (int j = 0; j < 8; ++j) {
                const float a = xl[2 + (j >> 2)][j & 3], b = xl[4 + (j >> 2)][j & 3], c = xl[6 + (j >> 2)][j & 3];
                vl[j] = a * r[kk] + b * r[3 + kk] + c * r[6 + kk];
            }
            stw(128 + kk * 128 + f0, pack8(vl));
        }
        {
            float nv[8];                                   // vec_norm -> k [512,640)
#pragma unroll
            for (int j = 0; j < 8; ++j) {
                const float a = xl[2 + (j >> 2)][j & 3], b = xl[4 + (j >> 2)][j & 3], c = xl[6 + (j >> 2)][j & 3];
                nv[j] = sqrtf(a * a + b * b + c * c + EPS_C);
            }
            stw(512 + f0, pack8(nv));
        }
#pragma unroll
        for (int q = 0; q < 4; ++q)                        // extra -> k [640,1152)
            stw(640 + l16 * 32 + q * 8, pack8v(el[2 * q], el[2 * q + 1]));
    }
    __syncthreads();   // full x1 image ready

    // ---------------- GEMM1 (32x32x16): wave w owns col-tiles {2w, 2w+1}; static ring-3 ----------------
    const float bw1a = b1[(2 * w)     * 32 + (lane & 31)];
    const float bw1b = b1[(2 * w + 1) * 32 + (lane & 31)];

    f32x16 acc00, acc01, acc10, acc11;
#pragma unroll
    for (int z = 0; z < 16; ++z) { acc00[z] = 0.f; acc01[z] = 0.f; acc10[z] = 0.f; acc11[z] = 0.f; }

    {
        const char* wbase = w1pc + ((size_t)(2 * w) * 1024) + lane * 16;   // frag (kt,nt) at (kt*32+nt)*1024 B
        auto LB = [&](bf16x8& B0, bf16x8& B1, int kt) {
            B0 = *reinterpret_cast<const bf16x8*>(wbase + (size_t)kt * 32768);
            B1 = *reinterpret_cast<const bf16x8*>(wbase + (size_t)kt * 32768 + 1024);
        };
        auto MM = [&](const bf16x8 B0, const bf16x8 B1, int kt) {
            const unsigned short* ap = buf + kt * 1024 + lane * 8;
            const bf16x8 A0 = *reinterpret_cast<const bf16x8*>(ap);
            const bf16x8 A1 = *reinterpret_cast<const bf16x8*>(ap + 512);
            __builtin_amdgcn_s_setprio(1);
            acc00 = MFMA32(A0, B0, acc00);
            acc01 = MFMA32(A0, B1, acc01);
            acc10 = MFMA32(A1, B0, acc10);
            acc11 = MFMA32(A1, B1, acc11);
            __builtin_amdgcn_s_setprio(0);
        };
        bf16x8 Ba0, Ba1, Bb0, Bb1, Bc0, Bc1;
        LB(Ba0, Ba1, 0); LB(Bb0, Bb1, 1);
#pragma unroll
        for (int kt = 0; kt < 72; kt += 3) {
            LB(Bc0, Bc1, kt + 2);
            MM(Ba0, Ba1, kt);
            if (kt + 3 < 72) LB(Ba0, Ba1, kt + 3);
            MM(Bb0, Bb1, kt + 1);
            if (kt + 4 < 72) LB(Bb0, Bb1, kt + 4);
            MM(Bc0, Bc1, kt + 2);
        }
    }
    __syncthreads();   // all x1 reads done; reuse buf[0..131072) as h fragments (16x16 layout)

    // ---------------- bias + GELU -> h frag-major (16x16 A-layout), cvt_pk pairs ----------------
    {
        const int hi5 = lane >> 5;          // C row group
        const int cz  = (lane & 31) >> 3;   // (col&31)>>3
        const int i7  = lane & 7;           // col&7
        auto GEL = [&](const f32x16& A, int mtl, int ntl, float bb) {
            const int ktn = 2 * w + ntl;
#pragma unroll
            for (int q = 0; q < 8; ++q) {
                const int reg  = 2 * q;                       // pair (reg, reg+1): rows rlo, rlo+1
                const int mt16 = mtl * 2 + (reg >> 3);
                const int rlo  = (reg & 3) + 8 * ((reg >> 2) & 1) + 4 * hi5;
                const unsigned pr = cvtpk(gelu_f(A[reg] + bb), gelu_f(A[reg + 1] + bb));
                unsigned short* p = &buf[(ktn * 4 + mt16) * 512 + (rlo + 16 * cz) * 8 + i7];
                p[0] = (unsigned short)pr;
                p[8] = (unsigned short)(pr >> 16);
            }
        };
        GEL(acc00, 0, 0, bw1a);
        GEL(acc01, 0, 1, bw1b);
        GEL(acc10, 1, 0, bw1a);
        GEL(acc11, 1, 1, bw1b);
    }
    __syncthreads();

    // ---------------- GEMM2 (16x16x32): wave (mh = w>>3) x (g = w&7); nt = {g, g+8, g+16, g+24}; static dbuf-2 ----------------
    const int mh = w >> 3;
    const int g  = w & 7;
    const int lr = lane & 15;
    const int lk = lane >> 4;

    f32x4 acc2[2][4];
#pragma unroll
    for (int mtl = 0; mtl < 2; ++mtl)
#pragma unroll
        for (int p = 0; p < 4; ++p) acc2[mtl][p] = (f32x4){0.f, 0.f, 0.f, 0.f};

    {
        const bf16x8* wb2 = w2p + (size_t)g * 64 + lane;
        auto LB2 = [&](bf16x8* C, int kt2) {
#pragma unroll
            for (int p = 0; p < 4; ++p) C[p] = wb2[(size_t)kt2 * 2048 + p * 512];
        };
        auto MM2 = [&](const bf16x8* C, int kt2) {
            const unsigned short* ab = buf + kt2 * 2048 + (mh * 2) * 512 + lane * 8;
            const bf16x8 a0 = *reinterpret_cast<const bf16x8*>(ab);
            const bf16x8 a1 = *reinterpret_cast<const bf16x8*>(ab + 512);
            __builtin_amdgcn_s_setprio(1);
#pragma unroll
            for (int p = 0; p < 4; ++p) {
                acc2[0][p] = MFMA16(a0, C[p], acc2[0][p]);
                acc2[1][p] = MFMA16(a1, C[p], acc2[1][p]);
            }
            __builtin_amdgcn_s_setprio(0);
        };
        bf16x8 Ca[4], Cb[4];
        LB2(Ca, 0);
#pragma unroll
        for (int kt2 = 0; kt2 < 32; kt2 += 2) {
            if (kt2 + 1 < 32) LB2(Cb, kt2 + 1);
            MM2(Ca, kt2);
            if (kt2 + 2 < 32) LB2(Ca, kt2 + 2);
            if (kt2 + 1 < 32) MM2(Cb, kt2 + 1);
        }
    }

    // ---------------- epilogue: in-register rotation + store ----------------
    {
        float bv2[4];
#pragma unroll
        for (int p = 0; p < 4; ++p) bv2[p] = b2[p * 128 + g * 16 + lr];
        const int fcol = g * 16 + lr;
#pragma unroll
        for (int mtl = 0; mtl < 2; ++mtl) {
#pragma unroll
            for (int j = 0; j < 4; ++j) {
                const int rl = (mh * 2 + mtl) * 16 + lk * 4 + j;
                if (row0 + rl < nrows) {
                    const float* Rp = R_s + rl * 9;
                    const float y0 = acc2[mtl][0][j] + bv2[0];
                    const float y1 = acc2[mtl][1][j] + bv2[1];
                    const float y2 = acc2[mtl][2][j] + bv2[2];
                    const float y3 = acc2[mtl][3][j] + bv2[3];
                    float* op = out + (size_t)(row0 + rl) * 512 + fcol;
                    op[0]   = y0;
                    op[128] = Rp[0] * y1 + Rp[1] * y2 + Rp[2] * y3;
                    op[256] = Rp[3] * y1 + Rp[4] * y2 + Rp[5] * y3;
                    op[384] = Rp[6] * y1 + Rp[7] * y2 + Rp[8] * y3;
                }
            }
        }
    }
}

extern "C" void kernel_launch(void* const* d_in, const int* in_sizes, int n_in,
                              void* d_out, int out_size, void* d_ws, size_t ws_size,
                              hipStream_t stream) {
    const float* x     = (const float*)d_in[0];
    const float* rot   = (const float*)d_in[1];
    const float* extra = (const float*)d_in[2];
    const float* W1    = (const float*)d_in[3];
    const float* b1    = (const float*)d_in[4];
    const float* W2    = (const float*)d_in[5];
    const float* b2    = (const float*)d_in[6];
    float* out = (float*)d_out;

    const int nrows = in_sizes[0] / 512;
    const int nblk  = (nrows + BMA - 1) / BMA;

    // ws: W1 packed (2304 KB) | W2 packed (1024 KB)
    unsigned short* w1p = (unsigned short*)d_ws;
    unsigned short* w2p = (unsigned short*)((char*)d_ws + (size_t)2304 * 1024);

    prep_kernel<<<(3328 * 64 + 255) / 256, 256, 0, stream>>>(W1, W2, w1p, w2p);

    fused_kernel<<<nblk, 1024, 0, stream>>>(x, rot, extra, b1, b2,
                                            (const char*)w1p, (const bf16x8*)w2p,
                                            out, nrows);
}